// Round 5
// baseline (1510.120 us; speedup 1.0000x reference)
//
#include <hip/hip_runtime.h>
#include <math.h>

#define NPERM 24
#define ND 256
#define RPB 48            // rows per block (one batch elem per block)
#define RPW 12            // rows per wave (4 waves)
#define ROWS_PER_B 576
#define BATCH 512
#define NBLOCKS (BATCH * ROWS_PER_B / RPB)   // 6144

// itertools.permutations(range(4)) — lexicographic order, with parity signs
__constant__ int c_P[NPERM * 4] = {
    0,1,2,3, 0,1,3,2, 0,2,1,3, 0,2,3,1, 0,3,1,2, 0,3,2,1,
    1,0,2,3, 1,0,3,2, 1,2,0,3, 1,2,3,0, 1,3,0,2, 1,3,2,0,
    2,0,1,3, 2,0,3,1, 2,1,0,3, 2,1,3,0, 2,3,0,1, 2,3,1,0,
    3,0,1,2, 3,0,2,1, 3,1,0,2, 3,1,2,0, 3,2,0,1, 3,2,1,0
};
__constant__ float c_S[NPERM] = {
     1.f,-1.f,-1.f, 1.f, 1.f,-1.f,
    -1.f, 1.f, 1.f,-1.f,-1.f, 1.f,
     1.f,-1.f,-1.f, 1.f, 1.f,-1.f,
    -1.f, 1.f, 1.f,-1.f,-1.f, 1.f
};

typedef float f2 __attribute__((ext_vector_type(2)));

// acc.{x,y} += y.x * w.{x,y}   (src0 low dword splat via op_sel)
__device__ __forceinline__ void pk_fma_lo(f2& acc, f2 y, f2 w) {
    asm("v_pk_fma_f32 %0, %1, %2, %0 op_sel:[0,0,0] op_sel_hi:[0,1,1]"
        : "+v"(acc) : "v"(y), "v"(w));
}
// acc.{x,y} += y.y * w.{x,y}   (src0 high dword splat via op_sel)
__device__ __forceinline__ void pk_fma_hi(f2& acc, f2 y, f2 w) {
    asm("v_pk_fma_f32 %0, %1, %2, %0 op_sel:[1,0,0] op_sel_hi:[1,1,1]"
        : "+v"(acc) : "v"(y), "v"(w));
}

__global__ __launch_bounds__(256, 2)
void fused_resnet(const float* __restrict__ x1, const float* __restrict__ x2,
                  const float* __restrict__ W0, const float* __restrict__ b0,
                  const float* __restrict__ W1, const float* __restrict__ b1,
                  const float* __restrict__ W2, const float* __restrict__ b2,
                  const float* __restrict__ Wf, const float* __restrict__ bf,
                  double* __restrict__ anti)
{
    __shared__ float sY[RPB * ND];     // 48 KB activations (f32, np-matching storage)
    __shared__ float sStage[4096];     // 16 KB: W tile; layer0 also feats at [2048..]
    const int t   = threadIdx.x;
    const int tc  = t & 63;            // col group: cols 4*tc..4*tc+3
    const int tr  = t >> 6;            // wave id: rows 12*tr..12*tr+11
    const int gr0 = blockIdx.x * RPB;
    const int b   = gr0 / ROWS_PER_B;

    // ---- build features into sStage[2048 + lr*24 + c] ----
    for (int e = t; e < RPB * 24; e += 256) {
        int lr = e / 24, c = e % 24;
        int pp = (gr0 + lr) % ROWS_PER_B;
        float v;
        if (c < 12) {
            int p1 = pp / 24;
            v = x1[b * 12 + c_P[p1 * 4 + c / 3] * 3 + (c % 3)];
        } else {
            int p2 = pp % 24; int cc = c - 12;
            v = x2[b * 12 + c_P[p2 * 4 + cc / 3] * 3 + (cc % 3)];
        }
        sStage[2048 + e] = v;
    }

    // packed accumulators: acc01[r] = cols {4tc, 4tc+1}, acc23[r] = {4tc+2, 4tc+3}
    // Each column keeps its own sequential fp32 FMA chain over k (np order).
    f2 acc01[RPW], acc23[RPW];

    // ---------- layer 0: 24 -> 256, tanh, no residual ----------
    #pragma unroll
    for (int r = 0; r < RPW; ++r) { acc01[r] = (f2)(0.f); acc23[r] = (f2)(0.f); }
    for (int kt = 0; kt < 24; kt += 8) {
        __syncthreads();
        {   // stage W0 rows [kt, kt+8): 2048 contiguous floats (cached loads!)
            const float4* src = (const float4*)(W0 + kt * ND);
            float4* dst = (float4*)sStage;
            for (int i = t; i < (8 * ND) / 4; i += 256) dst[i] = src[i];
        }
        __syncthreads();
        #pragma unroll
        for (int k4 = 0; k4 < 2; ++k4) {
            f2 wlo[4], whi[4];
            #pragma unroll
            for (int k = 0; k < 4; ++k) {
                float4 wv = *(const float4*)&sStage[(k4 * 4 + k) * ND + 4 * tc];
                wlo[k].x = wv.x; wlo[k].y = wv.y; whi[k].x = wv.z; whi[k].y = wv.w;
            }
            #pragma unroll
            for (int r = 0; r < RPW; ++r) {
                float4 yv = *(const float4*)&sStage[2048 + (tr * RPW + r) * 24 + kt + k4 * 4];
                f2 ylo; ylo.x = yv.x; ylo.y = yv.y;
                f2 yhi; yhi.x = yv.z; yhi.y = yv.w;
                pk_fma_lo(acc01[r], ylo, wlo[0]); pk_fma_lo(acc23[r], ylo, whi[0]);
                pk_fma_hi(acc01[r], ylo, wlo[1]); pk_fma_hi(acc23[r], ylo, whi[1]);
                pk_fma_lo(acc01[r], yhi, wlo[2]); pk_fma_lo(acc23[r], yhi, whi[2]);
                pk_fma_hi(acc01[r], yhi, wlo[3]); pk_fma_hi(acc23[r], yhi, whi[3]);
            }
        }
    }
    {
        float4 bv = *(const float4*)&b0[4 * tc];
        __syncthreads();
        #pragma unroll
        for (int r = 0; r < RPW; ++r) {
            float4 o;
            o.x = tanhf(acc01[r].x + bv.x);
            o.y = tanhf(acc01[r].y + bv.y);
            o.z = tanhf(acc23[r].x + bv.z);
            o.w = tanhf(acc23[r].y + bv.w);
            *(float4*)&sY[(tr * RPW + r) * ND + 4 * tc] = o;
        }
        __syncthreads();
    }

    // ---------- layers 1,2: 256 -> 256, tanh + residual ----------
    #pragma unroll 1
    for (int layer = 0; layer < 2; ++layer) {
        const float* W   = layer ? W2 : W1;
        const float* bbp = layer ? b2 : b1;
        #pragma unroll
        for (int r = 0; r < RPW; ++r) { acc01[r] = (f2)(0.f); acc23[r] = (f2)(0.f); }
        for (int kt = 0; kt < ND; kt += 16) {
            __syncthreads();
            {   // stage W rows [kt, kt+16): 4096 contiguous floats (cached loads!)
                const float4* src = (const float4*)(W + kt * ND);
                float4* dst = (float4*)sStage;
                #pragma unroll
                for (int i = 0; i < 4; ++i) dst[t + i * 256] = src[t + i * 256];
            }
            __syncthreads();
            #pragma unroll
            for (int k4 = 0; k4 < 4; ++k4) {
                f2 wlo[4], whi[4];
                #pragma unroll
                for (int k = 0; k < 4; ++k) {
                    float4 wv = *(const float4*)&sStage[(k4 * 4 + k) * ND + 4 * tc];
                    wlo[k].x = wv.x; wlo[k].y = wv.y; whi[k].x = wv.z; whi[k].y = wv.w;
                }
                #pragma unroll
                for (int r = 0; r < RPW; ++r) {
                    float4 yv = *(const float4*)&sY[(tr * RPW + r) * ND + kt + k4 * 4];
                    f2 ylo; ylo.x = yv.x; ylo.y = yv.y;
                    f2 yhi; yhi.x = yv.z; yhi.y = yv.w;
                    pk_fma_lo(acc01[r], ylo, wlo[0]); pk_fma_lo(acc23[r], ylo, whi[0]);
                    pk_fma_hi(acc01[r], ylo, wlo[1]); pk_fma_hi(acc23[r], ylo, whi[1]);
                    pk_fma_lo(acc01[r], yhi, wlo[2]); pk_fma_lo(acc23[r], yhi, whi[2]);
                    pk_fma_hi(acc01[r], yhi, wlo[3]); pk_fma_hi(acc23[r], yhi, whi[3]);
                }
            }
        }
        // epilogue: bias + tanh + residual (all fp32, np order)
        float4 bv = *(const float4*)&bbp[4 * tc];
        float ny[RPW][4];
        #pragma unroll
        for (int r = 0; r < RPW; ++r) {
            float4 yo = *(const float4*)&sY[(tr * RPW + r) * ND + 4 * tc];
            ny[r][0] = tanhf(acc01[r].x + bv.x) + yo.x;
            ny[r][1] = tanhf(acc01[r].y + bv.y) + yo.y;
            ny[r][2] = tanhf(acc23[r].x + bv.z) + yo.z;
            ny[r][3] = tanhf(acc23[r].y + bv.w) + yo.w;
        }
        __syncthreads();   // all reads of old sY complete before overwrite
        #pragma unroll
        for (int r = 0; r < RPW; ++r) {
            float4 o; o.x = ny[r][0]; o.y = ny[r][1]; o.z = ny[r][2]; o.w = ny[r][3];
            *(float4*)&sY[(tr * RPW + r) * ND + 4 * tc] = o;
        }
        __syncthreads();
    }

    // ---------- head ----------
    // Per-row fp32 sequential FMA chain over all 256 elements (np-matching
    // rounding; DO NOT pack/reorder), then EXACT f64 signed sum across rows.
    if (t < 64) {   // stage Wf into sStage[0..255]
        ((float4*)sStage)[t] = ((const float4*)Wf)[t];
    }
    __syncthreads();
    double contrib = 0.0;
    if (tc < RPW) {
        int row = tr * RPW + tc;
        const float* yrow = &sY[row * ND];
        float f = 0.f;
        #pragma unroll 8
        for (int k = 0; k < ND; ++k) f = fmaf(yrow[k], sStage[k], f);
        f += bf[0];
        int pp = (gr0 + row) % ROWS_PER_B;
        double s = (double)(c_S[pp / 24] * c_S[pp % 24]);
        contrib = s * (double)f;
    }
    #pragma unroll
    for (int off = 32; off > 0; off >>= 1) contrib += __shfl_xor(contrib, off, 64);
    if (tc == 0) atomicAdd(&anti[b], contrib);
}

__global__ void finalize_log(const double* __restrict__ anti, float* __restrict__ out) {
    int i = blockIdx.x * 256 + threadIdx.x;
    if (i < BATCH) out[i] = (float)log(fabs(anti[i]));
}

extern "C" void kernel_launch(void* const* d_in, const int* in_sizes, int n_in,
                              void* d_out, int out_size, void* d_ws, size_t ws_size,
                              hipStream_t stream) {
    const float* x1 = (const float*)d_in[0];
    const float* x2 = (const float*)d_in[1];
    const float* W0 = (const float*)d_in[2];
    const float* b0 = (const float*)d_in[3];
    const float* W1 = (const float*)d_in[4];
    const float* b1 = (const float*)d_in[5];
    const float* W2 = (const float*)d_in[6];
    const float* b2 = (const float*)d_in[7];
    const float* Wf = (const float*)d_in[8];
    const float* bf = (const float*)d_in[9];
    double* anti = (double*)d_ws;                   // 512 doubles of scratch
    float* out   = (float*)d_out;

    hipMemsetAsync(anti, 0, BATCH * sizeof(double), stream);
    fused_resnet<<<NBLOCKS, 256, 0, stream>>>(x1, x2, W0, b0, W1, b1, W2, b2, Wf, bf, anti);
    finalize_log<<<(BATCH + 255) / 256, 256, 0, stream>>>(anti, out);
}